// Round 11
// baseline (465.119 us; speedup 1.0000x reference)
//
#include <hip/hip_runtime.h>
#include <math.h>

#define NN 50000
#define E0 640000
#define ET 690000   // E0 + NN self loops
#define F1 128
#define D1 256      // 8 heads * 32
#define C2 16
#define MPAD 50048  // 391*128, padded node count for MFMA tiles
#define PADK 136    // 128 + 8 pad (breaks ds_read_b128 bank conflicts)
#define LOG2E 1.4426950408889634f
#define NBK1 782    // ceil(NN/64) node-blocks for agg1
#define CSRB 512    // csr kernel blocks (<= co-residency bound)
#define CH 98       // nodes per csr block (512*98 >= NN)

typedef _Float16 f16x8 __attribute__((ext_vector_type(8)));
typedef _Float16 h2 __attribute__((ext_vector_type(2)));
typedef __attribute__((ext_vector_type(4))) float f32x4;

__device__ __forceinline__ unsigned short f2h(float f) {
  union { _Float16 h; unsigned short u; } c;
  c.h = (_Float16)f;
  return c.u;
}
__device__ __forceinline__ float h2f(unsigned short u) {
  union { unsigned short u; _Float16 h; } c; c.u = u; return (float)c.h;
}
__device__ __forceinline__ h2 u2h2(unsigned u) {
  union { unsigned u; h2 h; } c; c.u = u; return c.h;
}
__device__ __forceinline__ unsigned h22u(h2 h) {
  union { h2 h; unsigned u; } c; c.h = h; return c.u;
}

// Global spin barrier: all CSRB blocks are co-resident (512 blocks, 2/CU).
__device__ __forceinline__ void gbar(int* bar, int target) {
  __syncthreads();
  if (threadIdx.x == 0) {
    __threadfence();                       // release: drain stores to L2
    atomicAdd(bar, 1);
    while (__hip_atomic_load(bar, __ATOMIC_RELAXED, __HIP_MEMORY_SCOPE_AGENT) < target)
      __builtin_amdgcn_s_sleep(1);
  }
  __syncthreads();
  __threadfence();                         // acquire: invalidate L1 on all waves
}

// ---------------- fused CSR build + weight convert ----------------
// P0: weights->fp16, degree hist | P1: scan -> offs + cursor | P2: scatter.
__global__ __launch_bounds__(256) void k_csr(
    const float* __restrict__ Wl, const float* __restrict__ Wr,
    const float* __restrict__ W2l, const float* __restrict__ W2r,
    const int* __restrict__ ei,
    unsigned short* __restrict__ wt, unsigned short* __restrict__ wt2,
    int* __restrict__ deg, int* __restrict__ offs,
    unsigned short* __restrict__ csr, int* __restrict__ part,
    int* __restrict__ bar) {
  const int b = blockIdx.x, t = threadIdx.x;
  const int gtid = b * 256 + t;
  // ---- P0: weight converts (73728 elems) + edge histogram ----
  for (int i = gtid; i < 512 * 128 + 32 * 256; i += CSRB * 256) {
    if (i < 512 * 128) {
      int n = i >> 7, k = i & 127;
      wt[i] = f2h((n < 256) ? Wl[k * 256 + n] : Wr[k * 256 + (n - 256)]);
    } else {
      int j = i - 512 * 128;
      int n = j >> 8, k = j & 255;
      wt2[j] = f2h((n < 16) ? W2l[k * 16 + n] : W2r[k * 16 + (n - 16)]);
    }
  }
  for (int e = gtid; e < ET; e += CSRB * 256) {
    int d = (e < E0) ? ei[E0 + e] : (e - E0);
    atomicAdd(&deg[d], 1);
  }
  gbar(bar, CSRB);
  // ---- P1: block-chunk scan ----
  __shared__ int lds[128];
  __shared__ int red[5];
  const int base = b * CH;
  const int i0 = base + t;
  int v = (t < CH && i0 < NN) ? deg[i0] : 0;
  if (t < 128) lds[t] = v;
  __syncthreads();
  for (int off = 1; off < 128; off <<= 1) {
    int u = (t >= off && t < 128) ? lds[t - off] : 0;
    __syncthreads();
    if (t < 128) lds[t] += u;
    __syncthreads();
  }
  const int sumb = lds[127];
  if (t == 0) part[b] = sumb;              // release via gbar's fence
  gbar(bar, 2 * CSRB);
  // prefix = sum part[0..b) (atomic loads bypass L1)
  int pp = 0;
  for (int i = t; i < b; i += 256)
    pp += __hip_atomic_load(&part[i], __ATOMIC_RELAXED, __HIP_MEMORY_SCOPE_AGENT);
  pp += __shfl_xor(pp, 1);  pp += __shfl_xor(pp, 2);  pp += __shfl_xor(pp, 4);
  pp += __shfl_xor(pp, 8);  pp += __shfl_xor(pp, 16); pp += __shfl_xor(pp, 32);
  if ((t & 63) == 0) red[t >> 6] = pp;
  __syncthreads();
  const int prefix = red[0] + red[1] + red[2] + red[3];
  if (t < CH && i0 < NN) {
    int excl = prefix + lds[t] - v;
    offs[i0] = excl;
    deg[i0] = excl;                        // deg becomes cursor
  }
  if (b == CSRB - 1 && t == 0) offs[NN] = prefix + sumb;
  gbar(bar, 3 * CSRB);
  // ---- P2: scatter ----
  for (int e = gtid; e < ET; e += CSRB * 256) {
    int s, d;
    if (e < E0) { s = ei[e]; d = ei[E0 + e]; } else { s = d = e - E0; }
    int pos = atomicAdd(&deg[d], 1);
    csr[pos] = (unsigned short)s;          // node ids < 65536
  }
}

// ---------------- Layer-1 GEMM via MFMA (fp16) ----------------
// C[M=50048, N=512] = x(f32, converted in staging) @ Wt^T.
// Outputs HEAD-MAJOR: out[head][node][32].
__global__ __launch_bounds__(256) void k_gemm1m(
    const float* __restrict__ x, const unsigned short* __restrict__ wt,
    unsigned short* __restrict__ xlh, unsigned short* __restrict__ xrh) {
  __shared__ unsigned short Al[128 * PADK];
  __shared__ unsigned short Bl[128 * PADK];
  const int t = threadIdx.x;
  const int m0 = blockIdx.x * 128;
  const int n0 = blockIdx.y * 128;
  {
    const int r = t >> 4;             // 0..15
    const int c = (t & 15) * 8;
#pragma unroll
    for (int p = 0; p < 8; ++p) {
      const int row = r + p * 16;
      const int rg = m0 + row;
      const float* xp = &x[(size_t)(rg < NN ? rg : NN - 1) * F1 + c];
      float4 lo = *(const float4*)xp;
      float4 hi = *(const float4*)(xp + 4);
      h2 q0 = h2{(_Float16)lo.x, (_Float16)lo.y};
      h2 q1 = h2{(_Float16)lo.z, (_Float16)lo.w};
      h2 q2 = h2{(_Float16)hi.x, (_Float16)hi.y};
      h2 q3 = h2{(_Float16)hi.z, (_Float16)hi.w};
      uint4 st; st.x = h22u(q0); st.y = h22u(q1); st.z = h22u(q2); st.w = h22u(q3);
      *(uint4*)&Al[row * PADK + c] = st;
      *(float4*)&Bl[row * PADK + c] = *(const float4*)&wt[(size_t)(n0 + row) * F1 + c];
    }
  }
  __syncthreads();
  const int wave = t >> 6, lane = t & 63;
  const int mw = (wave >> 1) * 64, nw = (wave & 1) * 64;
  const int fr = lane & 15, fq = lane >> 4;
  f32x4 acc[4][4] = {};
#pragma unroll
  for (int ks = 0; ks < 4; ++ks) {
    const int ko = ks * 32 + fq * 8;
    f16x8 a[4], b[4];
#pragma unroll
    for (int i = 0; i < 4; ++i)
      a[i] = *(const f16x8*)&Al[(mw + i * 16 + fr) * PADK + ko];
#pragma unroll
    for (int j = 0; j < 4; ++j)
      b[j] = *(const f16x8*)&Bl[(nw + j * 16 + fr) * PADK + ko];
#pragma unroll
    for (int i = 0; i < 4; ++i)
#pragma unroll
      for (int j = 0; j < 4; ++j)
        acc[i][j] = __builtin_amdgcn_mfma_f32_16x16x32_f16(a[i], b[j], acc[i][j], 0, 0, 0);
  }
  unsigned short* outp = (n0 < 256) ? xlh : xrh;
  const int cb = (n0 & 255) + nw + fr;
#pragma unroll
  for (int j = 0; j < 4; ++j) {
    const int col = cb + j * 16;
    const int head = col >> 5, f = col & 31;
    unsigned short* hp = outp + (size_t)head * NN * 32 + f;
#pragma unroll
    for (int i = 0; i < 4; ++i) {
      const int gm0 = m0 + mw + i * 16 + fq * 4;
#pragma unroll
      for (int r = 0; r < 4; ++r) {
        const int gm = gm0 + r;
        if (gm < NN) hp[(size_t)gm * 32] = f2h(acc[i][j][r]);
      }
    }
  }
}

// ---------------- Layer-1 aggregation (head-pinned, 16 nodes/wave) ----------------
// head = blockIdx&7 pins each head's 3.2 MB slice to one XCD L2 (validated
// R9/R10: FETCH 165->56 MB). One wave = 16 nodes x 1 head; each 4-lane group
// owns one node's edge loop; p group-uniform -> no epilogue reduction.
__global__ __launch_bounds__(256) void k_agg1(
    const unsigned short* __restrict__ xlh, const unsigned short* __restrict__ xrh,
    unsigned short* __restrict__ hb,
    const int* __restrict__ offs, const unsigned short* __restrict__ csr,
    const float* __restrict__ att, const float* __restrict__ b1) {
  const int b = blockIdx.x;
  const int head = b & 7;
  const int wave = threadIdx.x >> 6;
  const int lane = threadIdx.x & 63;
  const int g = lane >> 2;          // node group 0..15
  const int j4 = lane & 3;          // lane within group
  const int n = (b >> 3) * 64 + wave * 16 + g;
  const bool valid = n < NN;
  const int colh = j4 * 8;          // feat offset within head
  const int col = head * 32 + colh; // global feat col (att/b1)
  const unsigned short* xlhead = xlh + (size_t)head * NN * 32;

  const int nc = valid ? n : 0;
  const uint4 xru = *(const uint4*)&xrh[((size_t)head * NN + nc) * 32 + colh];
  h2 xr2[4];
  xr2[0] = u2h2(xru.x); xr2[1] = u2h2(xru.y);
  xr2[2] = u2h2(xru.z); xr2[3] = u2h2(xru.w);
  float at8[8];
  *(float4*)&at8[0] = *(const float4*)&att[col];
  *(float4*)&at8[4] = *(const float4*)&att[col + 4];
  h2 ath6[4], ath4[4];
#pragma unroll
  for (int j = 0; j < 4; ++j) {
    ath6[j] = h2{(_Float16)(at8[2 * j] * (0.6f * LOG2E)),
                 (_Float16)(at8[2 * j + 1] * (0.6f * LOG2E))};
    ath4[j] = h2{(_Float16)(at8[2 * j] * (0.4f * LOG2E)),
                 (_Float16)(at8[2 * j + 1] * (0.4f * LOG2E))};
  }
  float l = 0.f;
  h2 acc2[4] = {h2{0, 0}, h2{0, 0}, h2{0, 0}, h2{0, 0}};
  const int beg = valid ? offs[n] : 0;
  const int fin = valid ? offs[n + 1] : 0;

  auto score = [&](const h2* xh) -> float {
    float cv = 0.f, ca = 0.f;
#pragma unroll
    for (int j = 0; j < 4; ++j) {
      h2 v = xh[j] + xr2[j];
      h2 a = u2h2(h22u(v) & 0x7FFF7FFFu);       // |v| per half
      cv = __builtin_amdgcn_fdot2(v, ath6[j], cv, false);
      ca = __builtin_amdgcn_fdot2(a, ath4[j], ca, false);
    }
    float c = cv + ca;
    c += __shfl_xor(c, 1);
    c += __shfl_xor(c, 2);          // sum over the group's 4 lanes (32 feats)
    return c;
  };

  int idx = beg;
  for (; idx + 1 < fin; idx += 2) {
    const int s0 = csr[idx], s1 = csr[idx + 1];
    const uint4 w0 = *(const uint4*)&xlhead[(size_t)s0 * 32 + colh];
    const uint4 w1 = *(const uint4*)&xlhead[(size_t)s1 * 32 + colh];
    h2 xh0[4], xh1[4];
    xh0[0] = u2h2(w0.x); xh0[1] = u2h2(w0.y); xh0[2] = u2h2(w0.z); xh0[3] = u2h2(w0.w);
    xh1[0] = u2h2(w1.x); xh1[1] = u2h2(w1.y); xh1[2] = u2h2(w1.z); xh1[3] = u2h2(w1.w);
    const float c0 = score(xh0);
    const float c1 = score(xh1);
    const float p0 = exp2f(c0), p1 = exp2f(c1);
    l += p0 + p1;
    const _Float16 p0h = (_Float16)p0, p1h = (_Float16)p1;
    const h2 p02 = h2{p0h, p0h}, p12 = h2{p1h, p1h};
#pragma unroll
    for (int j = 0; j < 4; ++j) acc2[j] += p02 * xh0[j] + p12 * xh1[j];
  }
  if (idx < fin) {
    const int s0 = csr[idx];
    const uint4 w0 = *(const uint4*)&xlhead[(size_t)s0 * 32 + colh];
    h2 xh0[4];
    xh0[0] = u2h2(w0.x); xh0[1] = u2h2(w0.y); xh0[2] = u2h2(w0.z); xh0[3] = u2h2(w0.w);
    const float c0 = score(xh0);
    const float p0 = exp2f(c0);
    l += p0;
    const _Float16 p0h = (_Float16)p0;
    const h2 p02 = h2{p0h, p0h};
#pragma unroll
    for (int j = 0; j < 4; ++j) acc2[j] += p02 * xh0[j];
  }
  if (valid) {
    const float rl = 1.f / (l + 1e-16f);
    float b8[8], o[8];
    *(float4*)&b8[0] = *(const float4*)&b1[col];
    *(float4*)&b8[4] = *(const float4*)&b1[col + 4];
#pragma unroll
    for (int j = 0; j < 4; ++j) {
      o[2 * j]     = (float)acc2[j][0] * rl + b8[2 * j];
      o[2 * j + 1] = (float)acc2[j][1] * rl + b8[2 * j + 1];
    }
#pragma unroll
    for (int k = 0; k < 8; ++k) o[k] = o[k] > 0.f ? o[k] : expm1f(o[k]);
    ushort4 p;
    p.x = f2h(o[0]); p.y = f2h(o[1]); p.z = f2h(o[2]); p.w = f2h(o[3]);
    ushort4 q;
    q.x = f2h(o[4]); q.y = f2h(o[5]); q.z = f2h(o[6]); q.w = f2h(o[7]);
    uint4 packed;
    packed.x = *(unsigned*)&p.x; packed.y = *(unsigned*)&p.z;
    packed.z = *(unsigned*)&q.x; packed.w = *(unsigned*)&q.z;
    *(uint4*)&hb[(size_t)n * D1 + col] = packed;
  }
}

// ---------------- Layer-2 GEMM via MFMA (fp16, no LDS) ----------------
// h2[50000, 32] = hb @ Wt2^T. B fragments direct from global (wt2 is 16 KB,
// L1-resident). No barrier.
__global__ __launch_bounds__(256) void k_gemm2m(
    const unsigned short* __restrict__ hb, const unsigned short* __restrict__ wt2,
    unsigned short* __restrict__ h2lh, float* __restrict__ h2r) {
  const int t = threadIdx.x;
  const int wave = t >> 6, lane = t & 63;
  const int fr = lane & 15, fq = lane >> 4;
  const int m0 = blockIdx.x * 128 + wave * 32;
  f32x4 acc[2][2] = {};
#pragma unroll
  for (int ks = 0; ks < 8; ++ks) {
    const int ko = ks * 32 + fq * 8;
    f16x8 a[2], b[2];
#pragma unroll
    for (int i = 0; i < 2; ++i) {
      int row = m0 + i * 16 + fr; if (row >= NN) row = NN - 1;
      a[i] = *(const f16x8*)&hb[(size_t)row * D1 + ko];
    }
#pragma unroll
    for (int j = 0; j < 2; ++j)
      b[j] = *(const f16x8*)&wt2[(j * 16 + fr) * 256 + ko];
#pragma unroll
    for (int i = 0; i < 2; ++i)
#pragma unroll
      for (int j = 0; j < 2; ++j)
        acc[i][j] = __builtin_amdgcn_mfma_f32_16x16x32_f16(a[i], b[j], acc[i][j], 0, 0, 0);
  }
#pragma unroll
  for (int i = 0; i < 2; ++i) {
    const int gm0 = m0 + i * 16 + fq * 4;
#pragma unroll
    for (int r = 0; r < 4; ++r) {
      const int gm = gm0 + r;
      if (gm < NN) {
        h2lh[(size_t)gm * C2 + fr] = f2h(acc[i][0][r]);
        h2r[(size_t)gm * C2 + fr] = acc[i][1][r];
      }
    }
  }
}

// ---------------- Layer-2 aggregation ----------------
__global__ __launch_bounds__(256) void k_agg2(
    const unsigned short* __restrict__ h2lh, const float* __restrict__ h2r,
    const int* __restrict__ offs, const unsigned short* __restrict__ csr,
    const float* __restrict__ att2, const float* __restrict__ b2,
    float* __restrict__ out) {
  const int wave = threadIdx.x >> 6;
  const int lane = threadIdx.x & 63;
  const int n = blockIdx.x * 4 + wave;
  if (n >= NN) return;
  const int c = lane & 15, g = lane >> 4;
  const float xr_v = h2r[(size_t)n * C2 + c];
  const float att_v = att2[c] * LOG2E;
  float l = 0.f, acc = 0.f;
  const int beg = offs[n], fin = offs[n + 1];
  for (int idx = beg + g; idx < fin; idx += 4) {
    int s = csr[idx];
    float xlv = h2f(h2lh[(size_t)s * C2 + c]);
    float v = xlv + xr_v;
    v = fmaxf(v, 0.2f * v);
    float sc0 = v * att_v;
    sc0 += __shfl_xor(sc0, 1);
    sc0 += __shfl_xor(sc0, 2);
    sc0 += __shfl_xor(sc0, 4);
    sc0 += __shfl_xor(sc0, 8);
    float p = exp2f(sc0);
    l += p;
    acc = fmaf(p, xlv, acc);
  }
  l += __shfl_xor(l, 16);   l += __shfl_xor(l, 32);
  acc += __shfl_xor(acc, 16); acc += __shfl_xor(acc, 32);
  float o = acc / (l + 1e-16f) + b2[c];
  o = o > 0.f ? o : 0.01f * o;
  if (lane < 16) out[(size_t)n * C2 + c] = o;
}

extern "C" void kernel_launch(void* const* d_in, const int* in_sizes, int n_in,
                              void* d_out, int out_size, void* d_ws, size_t ws_size,
                              hipStream_t stream) {
  const float* x    = (const float*)d_in[0];
  const int*   ei   = (const int*)d_in[1];
  const float* W1l  = (const float*)d_in[2];
  const float* W1r  = (const float*)d_in[3];
  const float* att1 = (const float*)d_in[4];
  const float* b1   = (const float*)d_in[5];
  const float* W2l  = (const float*)d_in[6];
  const float* W2r  = (const float*)d_in[7];
  const float* att2 = (const float*)d_in[8];
  const float* b2   = (const float*)d_in[9];
  float* out = (float*)d_out;

  // Workspace layout (~79 MB):
  unsigned short* xlh = (unsigned short*)d_ws;        // [8][NN][32] fp16
  unsigned short* xrh = xlh + (size_t)NN * D1;        // [8][NN][32] fp16
  unsigned short* hb  = xrh + (size_t)NN * D1;        // [NN][256] fp16
  int* deg  = (int*)(hb + (size_t)NN * D1);           // NN (becomes cursor)
  int* part = deg + NN;                               // CSRB
  int* bar  = part + CSRB;                            // 1  (memset with deg/part)
  int* offs = bar + 1;                                // NN+1
  unsigned short* csr = (unsigned short*)(offs + NN + 1);  // ET u16
  unsigned short* wt  = csr + ET + 2;                 // 512*128 fp16
  unsigned short* wt2 = wt + 512 * F1;                // 32*256 fp16
  unsigned short* h2lh = xlh;                         // alias: xlh dead after agg1
  float* h2r = (float*)(h2lh + (size_t)NN * C2);

  hipMemsetAsync(deg, 0, (NN + CSRB + 1) * sizeof(int), stream);
  k_csr<<<CSRB, 256, 0, stream>>>(W1l, W1r, W2l, W2r, ei, wt, wt2,
                                  deg, offs, csr, part, bar);
  k_gemm1m<<<dim3(MPAD / 128, 4), 256, 0, stream>>>(x, wt, xlh, xrh);
  k_agg1<<<NBK1 * 8, 256, 0, stream>>>(xlh, xrh, hb, offs, csr, att1, b1);
  k_gemm2m<<<(NN + 127) / 128, 256, 0, stream>>>(hb, wt2, h2lh, h2r);
  k_agg2<<<NN / 4, 256, 0, stream>>>(h2lh, h2r, offs, csr, att2, b2, out);
}

// Round 12
// 270.208 us; speedup vs baseline: 1.7213x; 1.7213x over previous
//
#include <hip/hip_runtime.h>
#include <math.h>

#define NN 50000
#define E0 640000
#define ET 690000   // E0 + NN self loops
#define F1 128
#define D1 256      // 8 heads * 32
#define C2 16
#define NB 196      // ceil(NN/256)
#define MPAD 50048  // 391*128, padded node count for MFMA tiles
#define PADK 136    // 128 + 8 pad (breaks ds_read_b128 bank conflicts)
#define LOG2E 1.4426950408889634f
#define NBK1 782    // ceil(NN/64) node-blocks for agg1

typedef _Float16 f16x8 __attribute__((ext_vector_type(8)));
typedef _Float16 h2 __attribute__((ext_vector_type(2)));
typedef __attribute__((ext_vector_type(4))) float f32x4;

__device__ __forceinline__ unsigned short f2h(float f) {
  union { _Float16 h; unsigned short u; } c;
  c.h = (_Float16)f;
  return c.u;
}
__device__ __forceinline__ float h2f(unsigned short u) {
  union { unsigned short u; _Float16 h; } c; c.u = u; return (float)c.h;
}
__device__ __forceinline__ h2 u2h2(unsigned u) {
  union { unsigned u; h2 h; } c; c.u = u; return c.h;
}
__device__ __forceinline__ unsigned h22u(h2 h) {
  union { h2 h; unsigned u; } c; c.h = h; return c.u;
}

// ---------------- prep: weight converts + degree histogram ----------------
// blocks [0,256): wt | [256,288): wt2 | rest: edge histogram.
__global__ __launch_bounds__(256) void k_prep(
    const float* __restrict__ Wl, const float* __restrict__ Wr,
    const float* __restrict__ W2l, const float* __restrict__ W2r,
    const int* __restrict__ ei,
    unsigned short* __restrict__ wt, unsigned short* __restrict__ wt2,
    int* __restrict__ deg) {
  const int b = blockIdx.x;
  if (b < 256) {
    int tid = b * 256 + threadIdx.x;            // = n*128 + k
    int n = tid >> 7, k = tid & 127;
    float v = (n < 256) ? Wl[k * 256 + n] : Wr[k * 256 + (n - 256)];
    wt[tid] = f2h(v);
  } else if (b < 288) {
    int tid = (b - 256) * 256 + threadIdx.x;    // = n*256 + k
    int n = tid >> 8, k = tid & 255;
    float v = (n < 16) ? W2l[k * 16 + n] : W2r[k * 16 + (n - 16)];
    wt2[tid] = f2h(v);
  } else {
    int e = (b - 288) * 256 + threadIdx.x;
    if (e >= ET) return;
    int d = (e < E0) ? ei[E0 + e] : (e - E0);
    atomicAdd(&deg[d], 1);
  }
}

// ---------------- Layer-1 GEMM via MFMA (fp16) ----------------
// C[M=50048, N=512] = x(f32, converted in staging) @ Wt^T.
// Outputs HEAD-MAJOR: out[head][node][32].
__global__ __launch_bounds__(256) void k_gemm1m(
    const float* __restrict__ x, const unsigned short* __restrict__ wt,
    unsigned short* __restrict__ xlh, unsigned short* __restrict__ xrh) {
  __shared__ unsigned short Al[128 * PADK];
  __shared__ unsigned short Bl[128 * PADK];
  const int t = threadIdx.x;
  const int m0 = blockIdx.x * 128;
  const int n0 = blockIdx.y * 128;
  {
    const int r = t >> 4;             // 0..15
    const int c = (t & 15) * 8;
#pragma unroll
    for (int p = 0; p < 8; ++p) {
      const int row = r + p * 16;
      const int rg = m0 + row;
      const float* xp = &x[(size_t)(rg < NN ? rg : NN - 1) * F1 + c];
      float4 lo = *(const float4*)xp;
      float4 hi = *(const float4*)(xp + 4);
      h2 q0 = h2{(_Float16)lo.x, (_Float16)lo.y};
      h2 q1 = h2{(_Float16)lo.z, (_Float16)lo.w};
      h2 q2 = h2{(_Float16)hi.x, (_Float16)hi.y};
      h2 q3 = h2{(_Float16)hi.z, (_Float16)hi.w};
      uint4 st; st.x = h22u(q0); st.y = h22u(q1); st.z = h22u(q2); st.w = h22u(q3);
      *(uint4*)&Al[row * PADK + c] = st;
      *(float4*)&Bl[row * PADK + c] = *(const float4*)&wt[(size_t)(n0 + row) * F1 + c];
    }
  }
  __syncthreads();
  const int wave = t >> 6, lane = t & 63;
  const int mw = (wave >> 1) * 64, nw = (wave & 1) * 64;
  const int fr = lane & 15, fq = lane >> 4;
  f32x4 acc[4][4] = {};
#pragma unroll
  for (int ks = 0; ks < 4; ++ks) {
    const int ko = ks * 32 + fq * 8;
    f16x8 a[4], b[4];
#pragma unroll
    for (int i = 0; i < 4; ++i)
      a[i] = *(const f16x8*)&Al[(mw + i * 16 + fr) * PADK + ko];
#pragma unroll
    for (int j = 0; j < 4; ++j)
      b[j] = *(const f16x8*)&Bl[(nw + j * 16 + fr) * PADK + ko];
#pragma unroll
    for (int i = 0; i < 4; ++i)
#pragma unroll
      for (int j = 0; j < 4; ++j)
        acc[i][j] = __builtin_amdgcn_mfma_f32_16x16x32_f16(a[i], b[j], acc[i][j], 0, 0, 0);
  }
  unsigned short* outp = (n0 < 256) ? xlh : xrh;
  const int cb = (n0 & 255) + nw + fr;
#pragma unroll
  for (int j = 0; j < 4; ++j) {
    const int col = cb + j * 16;
    const int head = col >> 5, f = col & 31;
    unsigned short* hp = outp + (size_t)head * NN * 32 + f;
#pragma unroll
    for (int i = 0; i < 4; ++i) {
      const int gm0 = m0 + mw + i * 16 + fq * 4;
#pragma unroll
      for (int r = 0; r < 4; ++r) {
        const int gm = gm0 + r;
        if (gm < NN) hp[(size_t)gm * 32] = f2h(acc[i][j][r]);
      }
    }
  }
}

// ---------------- CSR scan/scatter ----------------
__global__ __launch_bounds__(256) void k_scan_part(const int* __restrict__ deg,
                                                   int* __restrict__ part) {
  int i = blockIdx.x * 256 + threadIdx.x;
  int v = (i < NN) ? deg[i] : 0;
  v += __shfl_xor(v, 1);  v += __shfl_xor(v, 2);  v += __shfl_xor(v, 4);
  v += __shfl_xor(v, 8);  v += __shfl_xor(v, 16); v += __shfl_xor(v, 32);
  __shared__ int w[4];
  if ((threadIdx.x & 63) == 0) w[threadIdx.x >> 6] = v;
  __syncthreads();
  if (threadIdx.x == 0) part[blockIdx.x] = w[0] + w[1] + w[2] + w[3];
}

// Block-local scan + inline prefix over part[0..b) (replaces scan_top).
__global__ __launch_bounds__(256) void k_scan_apply(int* __restrict__ deg,
                                                    const int* __restrict__ part,
                                                    int* __restrict__ offs) {
  __shared__ int lds[256];
  __shared__ int red[4];
  const int b = blockIdx.x, t = threadIdx.x;
  const int i = b * 256 + t;
  int v = (i < NN) ? deg[i] : 0;
  lds[t] = v;
  // prefix of preceding blocks' partial sums
  int pp = 0;
  for (int j = t; j < b; j += 256) pp += part[j];
  pp += __shfl_xor(pp, 1);  pp += __shfl_xor(pp, 2);  pp += __shfl_xor(pp, 4);
  pp += __shfl_xor(pp, 8);  pp += __shfl_xor(pp, 16); pp += __shfl_xor(pp, 32);
  if ((t & 63) == 0) red[t >> 6] = pp;
  __syncthreads();
  const int prefix = red[0] + red[1] + red[2] + red[3];
  for (int off = 1; off < 256; off <<= 1) {
    int u = (t >= off) ? lds[t - off] : 0;
    __syncthreads();
    lds[t] += u;
    __syncthreads();
  }
  int excl = prefix + lds[t] - v;
  if (i < NN) { offs[i] = excl; deg[i] = excl; }  // deg becomes cursor
  if (b == NB - 1 && t == 255) offs[NN] = prefix + lds[255];
}

__global__ void k_scatter(const int* __restrict__ ei, int* __restrict__ cur,
                          unsigned short* __restrict__ csr) {
  int e = blockIdx.x * 256 + threadIdx.x;
  if (e >= ET) return;
  int s, d;
  if (e < E0) { s = ei[e]; d = ei[E0 + e]; } else { s = d = e - E0; }
  int pos = atomicAdd(&cur[d], 1);
  csr[pos] = (unsigned short)s;   // node ids < 65536
}

// ---------------- Layer-1 aggregation (head-pinned, 16 nodes/wave) ----------------
// head = blockIdx&7 pins each head's 3.2 MB slice to one XCD L2 (validated
// R9/R10: FETCH 165->56 MB). One wave = 16 nodes x 1 head; each 4-lane group
// owns one node's edge loop; p group-uniform -> no epilogue reduction.
__global__ __launch_bounds__(256) void k_agg1(
    const unsigned short* __restrict__ xlh, const unsigned short* __restrict__ xrh,
    unsigned short* __restrict__ hb,
    const int* __restrict__ offs, const unsigned short* __restrict__ csr,
    const float* __restrict__ att, const float* __restrict__ b1) {
  const int b = blockIdx.x;
  const int head = b & 7;
  const int wave = threadIdx.x >> 6;
  const int lane = threadIdx.x & 63;
  const int g = lane >> 2;          // node group 0..15
  const int j4 = lane & 3;          // lane within group
  const int n = (b >> 3) * 64 + wave * 16 + g;
  const bool valid = n < NN;
  const int colh = j4 * 8;          // feat offset within head
  const int col = head * 32 + colh; // global feat col (att/b1)
  const unsigned short* xlhead = xlh + (size_t)head * NN * 32;

  const int nc = valid ? n : 0;
  const uint4 xru = *(const uint4*)&xrh[((size_t)head * NN + nc) * 32 + colh];
  h2 xr2[4];
  xr2[0] = u2h2(xru.x); xr2[1] = u2h2(xru.y);
  xr2[2] = u2h2(xru.z); xr2[3] = u2h2(xru.w);
  float at8[8];
  *(float4*)&at8[0] = *(const float4*)&att[col];
  *(float4*)&at8[4] = *(const float4*)&att[col + 4];
  h2 ath6[4], ath4[4];
#pragma unroll
  for (int j = 0; j < 4; ++j) {
    ath6[j] = h2{(_Float16)(at8[2 * j] * (0.6f * LOG2E)),
                 (_Float16)(at8[2 * j + 1] * (0.6f * LOG2E))};
    ath4[j] = h2{(_Float16)(at8[2 * j] * (0.4f * LOG2E)),
                 (_Float16)(at8[2 * j + 1] * (0.4f * LOG2E))};
  }
  float l = 0.f;
  h2 acc2[4] = {h2{0, 0}, h2{0, 0}, h2{0, 0}, h2{0, 0}};
  const int beg = valid ? offs[n] : 0;
  const int fin = valid ? offs[n + 1] : 0;

  auto score = [&](const h2* xh) -> float {
    float cv = 0.f, ca = 0.f;
#pragma unroll
    for (int j = 0; j < 4; ++j) {
      h2 v = xh[j] + xr2[j];
      h2 a = u2h2(h22u(v) & 0x7FFF7FFFu);       // |v| per half
      cv = __builtin_amdgcn_fdot2(v, ath6[j], cv, false);
      ca = __builtin_amdgcn_fdot2(a, ath4[j], ca, false);
    }
    float c = cv + ca;
    c += __shfl_xor(c, 1);
    c += __shfl_xor(c, 2);          // sum over the group's 4 lanes (32 feats)
    return c;
  };

  int idx = beg;
  for (; idx + 1 < fin; idx += 2) {
    const int s0 = csr[idx], s1 = csr[idx + 1];
    const uint4 w0 = *(const uint4*)&xlhead[(size_t)s0 * 32 + colh];
    const uint4 w1 = *(const uint4*)&xlhead[(size_t)s1 * 32 + colh];
    h2 xh0[4], xh1[4];
    xh0[0] = u2h2(w0.x); xh0[1] = u2h2(w0.y); xh0[2] = u2h2(w0.z); xh0[3] = u2h2(w0.w);
    xh1[0] = u2h2(w1.x); xh1[1] = u2h2(w1.y); xh1[2] = u2h2(w1.z); xh1[3] = u2h2(w1.w);
    const float c0 = score(xh0);
    const float c1 = score(xh1);
    const float p0 = exp2f(c0), p1 = exp2f(c1);
    l += p0 + p1;
    const _Float16 p0h = (_Float16)p0, p1h = (_Float16)p1;
    const h2 p02 = h2{p0h, p0h}, p12 = h2{p1h, p1h};
#pragma unroll
    for (int j = 0; j < 4; ++j) acc2[j] += p02 * xh0[j] + p12 * xh1[j];
  }
  if (idx < fin) {
    const int s0 = csr[idx];
    const uint4 w0 = *(const uint4*)&xlhead[(size_t)s0 * 32 + colh];
    h2 xh0[4];
    xh0[0] = u2h2(w0.x); xh0[1] = u2h2(w0.y); xh0[2] = u2h2(w0.z); xh0[3] = u2h2(w0.w);
    const float c0 = score(xh0);
    const float p0 = exp2f(c0);
    l += p0;
    const _Float16 p0h = (_Float16)p0;
    const h2 p02 = h2{p0h, p0h};
#pragma unroll
    for (int j = 0; j < 4; ++j) acc2[j] += p02 * xh0[j];
  }
  if (valid) {
    const float rl = 1.f / (l + 1e-16f);
    float b8[8], o[8];
    *(float4*)&b8[0] = *(const float4*)&b1[col];
    *(float4*)&b8[4] = *(const float4*)&b1[col + 4];
#pragma unroll
    for (int j = 0; j < 4; ++j) {
      o[2 * j]     = (float)acc2[j][0] * rl + b8[2 * j];
      o[2 * j + 1] = (float)acc2[j][1] * rl + b8[2 * j + 1];
    }
#pragma unroll
    for (int k = 0; k < 8; ++k) o[k] = o[k] > 0.f ? o[k] : expm1f(o[k]);
    ushort4 p;
    p.x = f2h(o[0]); p.y = f2h(o[1]); p.z = f2h(o[2]); p.w = f2h(o[3]);
    ushort4 q;
    q.x = f2h(o[4]); q.y = f2h(o[5]); q.z = f2h(o[6]); q.w = f2h(o[7]);
    uint4 packed;
    packed.x = *(unsigned*)&p.x; packed.y = *(unsigned*)&p.z;
    packed.z = *(unsigned*)&q.x; packed.w = *(unsigned*)&q.z;
    *(uint4*)&hb[(size_t)n * D1 + col] = packed;
  }
}

// ---------------- Layer-2 GEMM via MFMA (fp16, no LDS) ----------------
// h2[50000, 32] = hb @ Wt2^T. B fragments direct from global (wt2 is 16 KB,
// L1-resident). No barrier.
__global__ __launch_bounds__(256) void k_gemm2m(
    const unsigned short* __restrict__ hb, const unsigned short* __restrict__ wt2,
    unsigned short* __restrict__ h2lh, float* __restrict__ h2r) {
  const int t = threadIdx.x;
  const int wave = t >> 6, lane = t & 63;
  const int fr = lane & 15, fq = lane >> 4;
  const int m0 = blockIdx.x * 128 + wave * 32;
  f32x4 acc[2][2] = {};
#pragma unroll
  for (int ks = 0; ks < 8; ++ks) {
    const int ko = ks * 32 + fq * 8;
    f16x8 a[2], b[2];
#pragma unroll
    for (int i = 0; i < 2; ++i) {
      int row = m0 + i * 16 + fr; if (row >= NN) row = NN - 1;
      a[i] = *(const f16x8*)&hb[(size_t)row * D1 + ko];
    }
#pragma unroll
    for (int j = 0; j < 2; ++j)
      b[j] = *(const f16x8*)&wt2[(j * 16 + fr) * 256 + ko];
#pragma unroll
    for (int i = 0; i < 2; ++i)
#pragma unroll
      for (int j = 0; j < 2; ++j)
        acc[i][j] = __builtin_amdgcn_mfma_f32_16x16x32_f16(a[i], b[j], acc[i][j], 0, 0, 0);
  }
#pragma unroll
  for (int i = 0; i < 2; ++i) {
    const int gm0 = m0 + i * 16 + fq * 4;
#pragma unroll
    for (int r = 0; r < 4; ++r) {
      const int gm = gm0 + r;
      if (gm < NN) {
        h2lh[(size_t)gm * C2 + fr] = f2h(acc[i][0][r]);
        h2r[(size_t)gm * C2 + fr] = acc[i][1][r];
      }
    }
  }
}

// ---------------- Layer-2 aggregation ----------------
__global__ __launch_bounds__(256) void k_agg2(
    const unsigned short* __restrict__ h2lh, const float* __restrict__ h2r,
    const int* __restrict__ offs, const unsigned short* __restrict__ csr,
    const float* __restrict__ att2, const float* __restrict__ b2,
    float* __restrict__ out) {
  const int wave = threadIdx.x >> 6;
  const int lane = threadIdx.x & 63;
  const int n = blockIdx.x * 4 + wave;
  if (n >= NN) return;
  const int c = lane & 15, g = lane >> 4;
  const float xr_v = h2r[(size_t)n * C2 + c];
  const float att_v = att2[c] * LOG2E;
  float l = 0.f, acc = 0.f;
  const int beg = offs[n], fin = offs[n + 1];
  for (int idx = beg + g; idx < fin; idx += 4) {
    int s = csr[idx];
    float xlv = h2f(h2lh[(size_t)s * C2 + c]);
    float v = xlv + xr_v;
    v = fmaxf(v, 0.2f * v);
    float sc0 = v * att_v;
    sc0 += __shfl_xor(sc0, 1);
    sc0 += __shfl_xor(sc0, 2);
    sc0 += __shfl_xor(sc0, 4);
    sc0 += __shfl_xor(sc0, 8);
    float p = exp2f(sc0);
    l += p;
    acc = fmaf(p, xlv, acc);
  }
  l += __shfl_xor(l, 16);   l += __shfl_xor(l, 32);
  acc += __shfl_xor(acc, 16); acc += __shfl_xor(acc, 32);
  float o = acc / (l + 1e-16f) + b2[c];
  o = o > 0.f ? o : 0.01f * o;
  if (lane < 16) out[(size_t)n * C2 + c] = o;
}

extern "C" void kernel_launch(void* const* d_in, const int* in_sizes, int n_in,
                              void* d_out, int out_size, void* d_ws, size_t ws_size,
                              hipStream_t stream) {
  const float* x    = (const float*)d_in[0];
  const int*   ei   = (const int*)d_in[1];
  const float* W1l  = (const float*)d_in[2];
  const float* W1r  = (const float*)d_in[3];
  const float* att1 = (const float*)d_in[4];
  const float* b1   = (const float*)d_in[5];
  const float* W2l  = (const float*)d_in[6];
  const float* W2r  = (const float*)d_in[7];
  const float* att2 = (const float*)d_in[8];
  const float* b2   = (const float*)d_in[9];
  float* out = (float*)d_out;

  // Workspace layout (~79 MB):
  unsigned short* xlh = (unsigned short*)d_ws;        // [8][NN][32] fp16
  unsigned short* xrh = xlh + (size_t)NN * D1;        // [8][NN][32] fp16
  unsigned short* hb  = xrh + (size_t)NN * D1;        // [NN][256] fp16
  int* deg  = (int*)(hb + (size_t)NN * D1);           // NN (becomes cursor)
  int* part = deg + NN;                               // NB
  int* offs = part + NB;                              // NN+1
  unsigned short* csr = (unsigned short*)(offs + NN + 1);  // ET u16
  unsigned short* wt  = csr + ET + 2;                 // 512*128 fp16
  unsigned short* wt2 = wt + 512 * F1;                // 32*256 fp16
  unsigned short* h2lh = xlh;                         // alias: xlh dead after agg1
  float* h2r = (float*)(h2lh + (size_t)NN * C2);

  hipMemsetAsync(deg, 0, NN * sizeof(int), stream);
  k_prep<<<288 + (ET + 255) / 256, 256, 0, stream>>>(
      W1l, W1r, W2l, W2r, ei, wt, wt2, deg);
  k_gemm1m<<<dim3(MPAD / 128, 4), 256, 0, stream>>>(x, wt, xlh, xrh);
  k_scan_part<<<NB, 256, 0, stream>>>(deg, part);
  k_scan_apply<<<NB, 256, 0, stream>>>(deg, part, offs);
  k_scatter<<<(ET + 255) / 256, 256, 0, stream>>>(ei, deg, csr);
  k_agg1<<<NBK1 * 8, 256, 0, stream>>>(xlh, xrh, hb, offs, csr, att1, b1);
  k_gemm2m<<<(NN + 127) / 128, 256, 0, stream>>>(hb, wt2, h2lh, h2r);
  k_agg2<<<NN / 4, 256, 0, stream>>>(h2lh, h2r, offs, csr, att2, b2, out);
}